// Round 16
// baseline (93.965 us; speedup 1.0000x reference)
//
#include <hip/hip_runtime.h>

#define B_ 8
#define M_ 4096
#define E_ 1024
#define D_ 256
#define C_ 16

typedef unsigned short u16;
typedef unsigned int u32;
typedef float fv4 __attribute__((ext_vector_type(4)));
typedef short bh8 __attribute__((ext_vector_type(8)));

__device__ __forceinline__ float b2f(u16 v) { return __uint_as_float(((unsigned)v) << 16); }
__device__ __forceinline__ u16 f2b(float f) {
  unsigned u = __float_as_uint(f);
  return (u16)((u + 0x7FFFu + ((u >> 16) & 1u)) >> 16);
}
// packs lo -> low 16 bits, hi -> high 16 bits, RNE
__device__ __forceinline__ u32 cvtpk(float lo, float hi) {
  u32 r;
  asm("v_cvt_pk_bf16_f32 %0, %1, %2" : "=v"(r) : "v"(lo), "v"(hi));
  return r;
}
// per-row granule swizzle (16B granules, 8 per 64-u16 row segment)
__device__ __forceinline__ int xf(int r) { return ((r >> 2) ^ (r >> 5)) & 7; }

// ---------- split-K partial GEMM: P[kc] = inc^T @ nf over 512-m chunk ----------
// BM=256(e) x BN=256(d, full) x BK=64, split-K=8. Grid 256 = 8b x 4eb x 8kc.
// 512 threads = 8 waves (2x4 of 128x64 tiles). acc=128 VGPR/thread, LDS 147KB, 1 blk/CU.
// Staged volume: A x1 + B x4 = 269 MB total (vs 403 MB at BM=128).
__global__ __launch_bounds__(512, 1) void k_gemm0(const float* __restrict__ inc,
                                                  const float* __restrict__ nf,
                                                  float* __restrict__ P) {
  __shared__ u16 As[2][256][72];
  __shared__ u16 Bs[2][256][72];
  int f = blockIdx.x;
  int b = f & 7, s = f >> 3;
  int eb = s & 3, kc = s >> 2;  // kc 0..7, 512 m each
  int r0 = eb * 256;
  const float* Ab = inc + (long)b * M_ * E_ + (long)kc * 512 * E_;  // [m][e]
  const float* Bb = nf + (long)b * M_ * D_ + (long)kc * 512 * D_;   // [m][d]
  int t = threadIdx.x, l = t & 63, w = t >> 6;
  int l15 = l & 15, lg = l >> 4;
  int we = (w >> 2) * 128, wd = (w & 3) * 64;

  // staging: both tiles are 64 m-rows x 256 cols; thread owns 8 m-rows x 4 cols
  int mg = t >> 6;          // m-group 0..7 (rows mg*8 .. +7)
  int cc = (t & 63) * 4;    // col offset 0..252

  fv4 acc[8][4] = {};
  fv4 pa[8], pb[8];

  auto LOAD = [&](int k0) {
#pragma unroll
    for (int r = 0; r < 8; ++r) {
      int m = k0 + mg * 8 + r;
      pa[r] = *reinterpret_cast<const fv4*>(Ab + (long)m * E_ + r0 + cc);
      pb[r] = *reinterpret_cast<const fv4*>(Bb + (long)m * D_ + cc);
    }
  };
  auto WRITE = [&](int buf) {
#pragma unroll
    for (int j = 0; j < 4; ++j) {
      int col = cc + j;
      int colw = (mg ^ xf(col)) << 3;
      uint4 va, vb;
      va.x = cvtpk(pa[0][j], pa[1][j]);
      va.y = cvtpk(pa[2][j], pa[3][j]);
      va.z = cvtpk(pa[4][j], pa[5][j]);
      va.w = cvtpk(pa[6][j], pa[7][j]);
      vb.x = cvtpk(pb[0][j], pb[1][j]);
      vb.y = cvtpk(pb[2][j], pb[3][j]);
      vb.z = cvtpk(pb[4][j], pb[5][j]);
      vb.w = cvtpk(pb[6][j], pb[7][j]);
      *reinterpret_cast<uint4*>(&As[buf][col][colw]) = va;
      *reinterpret_cast<uint4*>(&Bs[buf][col][colw]) = vb;
    }
  };
  auto COMPUTE = [&](int buf) {
#pragma unroll
    for (int kk = 0; kk < 2; ++kk) {
      int gc = kk * 4 + lg;
      bh8 af[8], bf[4];
#pragma unroll
      for (int i = 0; i < 8; ++i) {
        int e = we + i * 16 + l15;
        af[i] = *reinterpret_cast<const bh8*>(&As[buf][e][(gc ^ xf(e)) << 3]);
      }
#pragma unroll
      for (int jj = 0; jj < 4; ++jj) {
        int d = wd + jj * 16 + l15;
        bf[jj] = *reinterpret_cast<const bh8*>(&Bs[buf][d][(gc ^ xf(d)) << 3]);
      }
#pragma unroll
      for (int i = 0; i < 8; ++i)
#pragma unroll
        for (int jj = 0; jj < 4; ++jj)
          acc[i][jj] = __builtin_amdgcn_mfma_f32_16x16x32_bf16(af[i], bf[jj], acc[i][jj], 0, 0, 0);
    }
  };

  LOAD(0);
  WRITE(0);
  __syncthreads();
  const int NIT = 8;  // 512 / 64
  for (int kt = 0; kt < NIT; ++kt) {
    if (kt < NIT - 1) LOAD((kt + 1) * 64);
    COMPUTE(kt & 1);
    if (kt < NIT - 1) {
      WRITE((kt + 1) & 1);
      __syncthreads();
    }
  }

  float* Pp = P + ((long)(kc * B_ + b) * E_ + r0) * D_;
#pragma unroll
  for (int i = 0; i < 8; ++i)
#pragma unroll
    for (int jj = 0; jj < 4; ++jj)
#pragma unroll
      for (int q = 0; q < 4; ++q) {
        int row = we + i * 16 + lg * 4 + q;
        int col = wd + jj * 16 + l15;
        Pp[(long)row * D_ + col] = acc[i][jj][q];
      }
}

// ---------- reduce 8 split-K partials -> G bf16 ----------
__global__ __launch_bounds__(256) void k_red(const float* __restrict__ P, u16* __restrict__ G) {
  const long CS = (long)B_ * E_ * D_;
  long i = ((long)blockIdx.x * 256 + threadIdx.x) * 4;
  fv4 s0 = *reinterpret_cast<const fv4*>(P + i);
  fv4 s1 = *reinterpret_cast<const fv4*>(P + CS + i);
  fv4 s2 = *reinterpret_cast<const fv4*>(P + 2 * CS + i);
  fv4 s3 = *reinterpret_cast<const fv4*>(P + 3 * CS + i);
  fv4 s4 = *reinterpret_cast<const fv4*>(P + 4 * CS + i);
  fv4 s5 = *reinterpret_cast<const fv4*>(P + 5 * CS + i);
  fv4 s6 = *reinterpret_cast<const fv4*>(P + 6 * CS + i);
  fv4 s7 = *reinterpret_cast<const fv4*>(P + 7 * CS + i);
  fv4 sum = ((s0 + s1) + (s2 + s3)) + ((s4 + s5) + (s6 + s7));
  uint2 o;
  o.x = cvtpk(sum[0], sum[1]);
  o.y = cvtpk(sum[2], sum[3]);
  *reinterpret_cast<uint2*>(G + i) = o;
}

// ---------- small-K GEMM: out = A' @ W^T (W read f32, converted on the fly) ----------
// MODE 2: A'=G bf16, write S f32 + per-block column softmax partial stats (seg y of 16).
// MODE 1: A'=H=G*exp(S-mx)*sv; mx/sv computed in prologue from mxp/smp (cstats fused);
//         ef = alpha*edge+(1-alpha)*C; fused z-partials -> zp.
template <int MODE>
__global__ __launch_bounds__(256, 2) void k_gemmS(
    const u16* __restrict__ A, const float* __restrict__ Wf,
    const float* __restrict__ Sin,
    float* __restrict__ Sout, float* __restrict__ mxp, float* __restrict__ smp,
    const float* __restrict__ edge, const float* __restrict__ alphap,
    float* __restrict__ outEF, const float* __restrict__ attw, float* __restrict__ zp) {
  __shared__ u16 As[2][64][72];
  __shared__ u16 Bs[2][64][72];
  __shared__ float sM[2][64], sS[2][64];
  __shared__ float sMx[D_], sSv[D_];
  int f = blockIdx.x;
  int b = f & 7, s = f >> 3;
  int x = s & 3, y = s >> 2;
  int r0 = y * 64, c0 = x * 64;
  const u16* Ab = A + (long)b * E_ * D_;
  int t = threadIdx.x, l = t & 63, w = t >> 6;
  int wr = w >> 1, wc = w & 1;
  int l15 = l & 15, lg = l >> 4;
  int rA = t >> 2, kA = (t & 3) * 16;

  if (MODE == 1) {
    float M = -3.0e38f;
#pragma unroll
    for (int s2 = 0; s2 < 16; ++s2) M = fmaxf(M, mxp[(b * 16 + s2) * D_ + t]);
    float Ssum = 0.f;
#pragma unroll
    for (int s2 = 0; s2 < 16; ++s2)
      Ssum += smp[(b * 16 + s2) * D_ + t] * __expf(mxp[(b * 16 + s2) * D_ + t] - M);
    sMx[t] = M;
    sSv[t] = 1.0f / Ssum;
  }
  __syncthreads();

  fv4 acc[2][2] = {};
  bh8 ga0[2], ga1[2];
  fv4 gb0[4], gb1[4];
  fv4 sa0[4], sa1[4];

  auto LOAD = [&](int k0, bh8 (&ga)[2], fv4 (&gb)[4], fv4 (&sa)[4]) {
    const u16* ap = Ab + (long)(r0 + rA) * D_ + k0 + kA;
    const float* bp = Wf + (long)(c0 + rA) * D_ + k0 + kA;
    ga[0] = *reinterpret_cast<const bh8*>(ap);
    ga[1] = *reinterpret_cast<const bh8*>(ap + 8);
#pragma unroll
    for (int i = 0; i < 4; ++i) gb[i] = *reinterpret_cast<const fv4*>(bp + i * 4);
    if (MODE == 1) {
      const float* sp2 = Sin + ((long)b * E_ + r0 + rA) * D_ + k0 + kA;
#pragma unroll
      for (int i = 0; i < 4; ++i) sa[i] = *reinterpret_cast<const fv4*>(sp2 + i * 4);
    }
  };
  auto WRITE = [&](const bh8 (&ga)[2], const fv4 (&gb)[4], const fv4 (&sa)[4], int buf, int k0) {
    if (MODE == 2) {
      *reinterpret_cast<bh8*>(&As[buf][rA][kA]) = ga[0];
      *reinterpret_cast<bh8*>(&As[buf][rA][kA + 8]) = ga[1];
    } else {
#pragma unroll
      for (int h = 0; h < 2; ++h) {
        fv4 mA = *reinterpret_cast<const fv4*>(&sMx[k0 + kA + h * 8]);
        fv4 mB = *reinterpret_cast<const fv4*>(&sMx[k0 + kA + h * 8 + 4]);
        fv4 vA = *reinterpret_cast<const fv4*>(&sSv[k0 + kA + h * 8]);
        fv4 vB = *reinterpret_cast<const fv4*>(&sSv[k0 + kA + h * 8 + 4]);
        float hf[8];
#pragma unroll
        for (int j = 0; j < 4; ++j) {
          hf[j]     = b2f((u16)ga[h][j])     * __expf(sa[h * 2][j]     - mA[j]) * vA[j];
          hf[4 + j] = b2f((u16)ga[h][j + 4]) * __expf(sa[h * 2 + 1][j] - mB[j]) * vB[j];
        }
        union { u32 w4[4]; bh8 v; } hp;
        hp.w4[0] = cvtpk(hf[0], hf[1]);
        hp.w4[1] = cvtpk(hf[2], hf[3]);
        hp.w4[2] = cvtpk(hf[4], hf[5]);
        hp.w4[3] = cvtpk(hf[6], hf[7]);
        *reinterpret_cast<bh8*>(&As[buf][rA][kA + h * 8]) = hp.v;
      }
    }
    union { u32 w4[4]; bh8 v; } wb0, wb1;
    wb0.w4[0] = cvtpk(gb[0][0], gb[0][1]);
    wb0.w4[1] = cvtpk(gb[0][2], gb[0][3]);
    wb0.w4[2] = cvtpk(gb[1][0], gb[1][1]);
    wb0.w4[3] = cvtpk(gb[1][2], gb[1][3]);
    wb1.w4[0] = cvtpk(gb[2][0], gb[2][1]);
    wb1.w4[1] = cvtpk(gb[2][2], gb[2][3]);
    wb1.w4[2] = cvtpk(gb[3][0], gb[3][1]);
    wb1.w4[3] = cvtpk(gb[3][2], gb[3][3]);
    *reinterpret_cast<bh8*>(&Bs[buf][rA][kA]) = wb0.v;
    *reinterpret_cast<bh8*>(&Bs[buf][rA][kA + 8]) = wb1.v;
  };
  auto COMPUTE = [&](int buf) {
#pragma unroll
    for (int kk = 0; kk < 2; ++kk) {
      bh8 af[2], bf[2];
#pragma unroll
      for (int i = 0; i < 2; ++i)
        af[i] = *reinterpret_cast<const bh8*>(&As[buf][wr * 32 + i * 16 + l15][kk * 32 + lg * 8]);
#pragma unroll
      for (int j = 0; j < 2; ++j)
        bf[j] = *reinterpret_cast<const bh8*>(&Bs[buf][wc * 32 + j * 16 + l15][kk * 32 + lg * 8]);
#pragma unroll
      for (int i = 0; i < 2; ++i)
#pragma unroll
        for (int j = 0; j < 2; ++j)
          acc[i][j] = __builtin_amdgcn_mfma_f32_16x16x32_bf16(af[i], bf[j], acc[i][j], 0, 0, 0);
    }
  };

  const int NT = D_ / 64;
  LOAD(0, ga0, gb0, sa0);
  LOAD(64, ga1, gb1, sa1);
  WRITE(ga0, gb0, sa0, 0, 0);
  __syncthreads();
  for (int kt = 0; kt < NT; kt += 2) {
    if (kt + 2 < NT) LOAD((kt + 2) * 64, ga0, gb0, sa0);
    COMPUTE(0);
    WRITE(ga1, gb1, sa1, 1, (kt + 1) * 64);
    __syncthreads();
    if (kt + 3 < NT) LOAD((kt + 3) * 64, ga1, gb1, sa1);
    COMPUTE(1);
    if (kt + 2 < NT) WRITE(ga0, gb0, sa0, 0, (kt + 2) * 64);
    __syncthreads();
  }

  if (MODE == 2) {
#pragma unroll
    for (int i = 0; i < 2; ++i)
#pragma unroll
      for (int j = 0; j < 2; ++j)
#pragma unroll
        for (int q = 0; q < 4; ++q) {
          int row = r0 + wr * 32 + i * 16 + lg * 4 + q;
          int col = c0 + wc * 32 + j * 16 + l15;
          Sout[((long)b * E_ + row) * D_ + col] = acc[i][j][q];
        }
#pragma unroll
    for (int j = 0; j < 2; ++j) {
      float m = -3.0e38f;
#pragma unroll
      for (int i = 0; i < 2; ++i)
#pragma unroll
        for (int q = 0; q < 4; ++q) m = fmaxf(m, acc[i][j][q]);
      m = fmaxf(m, __shfl_xor(m, 16));
      m = fmaxf(m, __shfl_xor(m, 32));
      float ssum = 0.f;
#pragma unroll
      for (int i = 0; i < 2; ++i)
#pragma unroll
        for (int q = 0; q < 4; ++q) ssum += __expf(acc[i][j][q] - m);
      ssum += __shfl_xor(ssum, 16);
      ssum += __shfl_xor(ssum, 32);
      if (lg == 0) {
        sM[wr][wc * 32 + j * 16 + l15] = m;
        sS[wr][wc * 32 + j * 16 + l15] = ssum;
      }
    }
    __syncthreads();
    if (t < 64) {
      float m0 = sM[0][t], m1 = sM[1][t];
      float M = fmaxf(m0, m1);
      float ss = sS[0][t] * __expf(m0 - M) + sS[1][t] * __expf(m1 - M);
      int idx = (b * 16 + y) * D_ + c0 + t;
      mxp[idx] = M;
      smp[idx] = ss;
    }
  } else {
    float al = *alphap, oneal = 1.0f - al;
    float aw0 = attw[c0 + wc * 32 + l15];
    float aw1 = attw[c0 + wc * 32 + 16 + l15];
#pragma unroll
    for (int i = 0; i < 2; ++i)
#pragma unroll
      for (int q = 0; q < 4; ++q) {
        int row = r0 + wr * 32 + i * 16 + lg * 4 + q;
        long idx0 = ((long)b * E_ + row) * D_ + c0 + wc * 32 + l15;
        long idx1 = idx0 + 16;
        float ef0 = al * edge[idx0] + oneal * acc[i][0][q];
        float ef1 = al * edge[idx1] + oneal * acc[i][1][q];
        outEF[idx0] = ef0;
        outEF[idx1] = ef1;
        float zv = ef0 * aw0 + ef1 * aw1;
        zv += __shfl_xor(zv, 1);
        zv += __shfl_xor(zv, 2);
        zv += __shfl_xor(zv, 4);
        zv += __shfl_xor(zv, 8);
        if (l15 == 0) zp[((long)(x * 2 + wc) * B_ + b) * E_ + row] = zv;
      }
  }
}

// ---------- tail A: redundant z-softmax + partial pooled over 128 e-rows ----------
__global__ __launch_bounds__(256) void k_tailA(const float* __restrict__ zp, const float* __restrict__ ef,
                                               float* __restrict__ pp) {
  int seg = blockIdx.x, b = blockIdx.y;
  int t = threadIdx.x;
  __shared__ float sZ[E_];
  __shared__ float wred[4];
  __shared__ float ps[4][D_];
  fv4 v = {};
#pragma unroll
  for (int s = 0; s < 8; ++s)
    v += *reinterpret_cast<const fv4*>(zp + ((long)s * B_ + b) * E_ + t * 4);
  *reinterpret_cast<fv4*>(&sZ[t * 4]) = v;
  float m = fmaxf(fmaxf(v[0], v[1]), fmaxf(v[2], v[3]));
#pragma unroll
  for (int off = 32; off; off >>= 1) m = fmaxf(m, __shfl_xor(m, off));
  if ((t & 63) == 0) wred[t >> 6] = m;
  __syncthreads();
  m = fmaxf(fmaxf(wred[0], wred[1]), fmaxf(wred[2], wred[3]));
  float e0 = __expf(v[0] - m), e1 = __expf(v[1] - m), e2 = __expf(v[2] - m), e3 = __expf(v[3] - m);
  float ssum = e0 + e1 + e2 + e3;
#pragma unroll
  for (int off = 32; off; off >>= 1) ssum += __shfl_xor(ssum, off);
  __syncthreads();
  if ((t & 63) == 0) wred[t >> 6] = ssum;
  __syncthreads();
  ssum = wred[0] + wred[1] + wred[2] + wred[3];
  float inv = 1.0f / ssum;
  fv4 az;
  az[0] = e0 * inv; az[1] = e1 * inv; az[2] = e2 * inv; az[3] = e3 * inv;
  __syncthreads();
  *reinterpret_cast<fv4*>(&sZ[t * 4]) = az;
  __syncthreads();
  int g = t >> 6, l = t & 63;
  fv4 a = {};
  const float* efb = ef + ((long)b * E_ + seg * 128 + g * 32) * D_ + l * 4;
  const float* azp = &sZ[seg * 128 + g * 32];
#pragma unroll 4
  for (int i = 0; i < 32; ++i)
    a += azp[i] * *reinterpret_cast<const fv4*>(efb + (long)i * D_);
  *reinterpret_cast<fv4*>(&ps[g][l * 4]) = a;
  __syncthreads();
  if (t < D_)
    pp[((long)b * 8 + seg) * D_ + t] = ps[0][t] + ps[1][t] + ps[2][t] + ps[3][t];
}

// ---------- tail B: pooled = sum segs; proj; fc -> logits ----------
__global__ __launch_bounds__(256) void k_tailB(const float* __restrict__ pp,
                                               const float* __restrict__ projw, const float* __restrict__ projb,
                                               const float* __restrict__ fcw, const float* __restrict__ fcb,
                                               float* __restrict__ outp) {
  int b = blockIdx.x, t = threadIdx.x;
  __shared__ float spl[D_], ov[D_];
  float a = 0.f;
#pragma unroll
  for (int s = 0; s < 8; ++s) a += pp[((long)b * 8 + s) * D_ + t];
  spl[t] = a;
  __syncthreads();
  float o = projb[t];
  const fv4* pw = reinterpret_cast<const fv4*>(projw + (long)t * D_);
#pragma unroll 8
  for (int dd = 0; dd < D_ / 4; ++dd) {
    fv4 wv = pw[dd];
    fv4 pv = *reinterpret_cast<const fv4*>(&spl[dd * 4]);
    o += wv[0] * pv[0] + wv[1] * pv[1] + wv[2] * pv[2] + wv[3] * pv[3];
  }
  ov[t] = o;
  __syncthreads();
  if (t < C_) {
    float lg = fcb[t];
    const fv4* fw = reinterpret_cast<const fv4*>(fcw + (long)t * D_);
#pragma unroll 8
    for (int dd = 0; dd < D_ / 4; ++dd) {
      fv4 wv = fw[dd];
      fv4 pv = *reinterpret_cast<const fv4*>(&ov[dd * 4]);
      lg += wv[0] * pv[0] + wv[1] * pv[1] + wv[2] * pv[2] + wv[3] * pv[3];
    }
    outp[b * C_ + t] = lg;
  }
}

extern "C" void kernel_launch(void* const* d_in, const int* in_sizes, int n_in,
                              void* d_out, int out_size, void* d_ws, size_t ws_size,
                              hipStream_t stream) {
  const float* node  = (const float*)d_in[0];
  const float* edge  = (const float*)d_in[1];
  const float* inc   = (const float*)d_in[2];
  const float* Wa    = (const float*)d_in[3];
  const float* Wp    = (const float*)d_in[4];
  const float* alpha = (const float*)d_in[5];
  const float* attw  = (const float*)d_in[6];
  const float* projw = (const float*)d_in[7];
  const float* projb = (const float*)d_in[8];
  const float* fcw   = (const float*)d_in[9];
  const float* fcb   = (const float*)d_in[10];
  float* outp = (float*)d_out;

  char* wsp = (char*)d_ws;
  size_t off = 0;
  auto alloc = [&](size_t bytes) {
    char* p = wsp + off;
    off += (bytes + 255) & ~(size_t)255;
    return (void*)p;
  };
  // P (8 x 8.4MB) dead after k_red; S and ef alias the region.
  float* P  = (float*)alloc((size_t)8 * B_ * E_ * D_ * 4);
  float* S  = P;                                  // written after k_red (P dead)
  float* ef = P + (size_t)2 * B_ * E_ * D_;       // written while S (lower region) is read
  u16* G    = (u16*)alloc((size_t)B_ * E_ * D_ * 2);
  float* mxp = (float*)alloc((size_t)B_ * 16 * D_ * 4);
  float* smp = (float*)alloc((size_t)B_ * 16 * D_ * 4);
  float* zp  = (float*)alloc((size_t)8 * B_ * E_ * 4);
  float* pp  = (float*)alloc((size_t)B_ * 8 * D_ * 4);

  // 1. split-K partials P[kc] = inc^T @ nf (BM256xBN256, 269MB staged)
  k_gemm0<<<dim3(256), 512, 0, stream>>>(inc, node, P);
  // 2. reduce 8 partials -> G bf16
  k_red<<<dim3((B_ * E_ * D_) / 1024), 256, 0, stream>>>(P, G);
  // 3. S = G @ Wa^T (f32, Wa converted on the fly) + partial column softmax stats
  k_gemmS<2><<<dim3(512), 256, 0, stream>>>(G, Wa, nullptr,
                                            S, mxp, smp, nullptr, nullptr, nullptr, nullptr, nullptr);
  // 4. ef = alpha*edge + (1-alpha)*((G*softmax) @ Wp^T); cstats + z-partials fused
  k_gemmS<1><<<dim3(512), 256, 0, stream>>>(G, Wp, S,
                                            nullptr, mxp, smp, edge, alpha, ef, attw, zp);
  // 5. tail A: redundant z-softmax + partial pooled (64 blocks)
  k_tailA<<<dim3(8, B_), 256, 0, stream>>>(zp, ef, pp);
  // 6. tail B: combine + proj + logits
  k_tailB<<<dim3(B_), 256, 0, stream>>>(pp, projw, projb, fcw, fcb, outp);
}

// Round 17
// 90.877 us; speedup vs baseline: 1.0340x; 1.0340x over previous
//
#include <hip/hip_runtime.h>

#define B_ 8
#define M_ 4096
#define E_ 1024
#define D_ 256
#define C_ 16

typedef unsigned short u16;
typedef unsigned int u32;
typedef float fv4 __attribute__((ext_vector_type(4)));
typedef short bh8 __attribute__((ext_vector_type(8)));

__device__ __forceinline__ float b2f(u16 v) { return __uint_as_float(((unsigned)v) << 16); }
__device__ __forceinline__ u16 f2b(float f) {
  unsigned u = __float_as_uint(f);
  return (u16)((u + 0x7FFFu + ((u >> 16) & 1u)) >> 16);
}
// packs lo -> low 16 bits, hi -> high 16 bits, RNE
__device__ __forceinline__ u32 cvtpk(float lo, float hi) {
  u32 r;
  asm("v_cvt_pk_bf16_f32 %0, %1, %2" : "=v"(r) : "v"(lo), "v"(hi));
  return r;
}
// per-row granule swizzle (16B granules, 8 per 64-u16 row segment)
__device__ __forceinline__ int xf(int r) { return ((r >> 2) ^ (r >> 5)) & 7; }

// ---------- split-K partial GEMM: P[kc] = inc^T @ nf over m-chunk (r11/r15 verbatim) ----------
// BM=128(e) x BN=256(d, full) x BK=64, split-K=4 (1024 m each).
// 512 threads = 8 waves (2x4 of 64x64 tiles). Grid 256, b=f&7 (batch per XCD).
__global__ __launch_bounds__(512, 2) void k_gemm0(const float* __restrict__ inc,
                                                  const float* __restrict__ nf,
                                                  float* __restrict__ P) {
  __shared__ u16 As[2][128][72];
  __shared__ u16 Bs[2][256][72];
  int f = blockIdx.x;
  int b = f & 7, s = f >> 3;
  int eb = s & 7, kc = s >> 3;
  int r0 = eb * 128;
  const float* Ab = inc + (long)b * M_ * E_ + (long)kc * 1024 * E_;  // [m][e]
  const float* Bb = nf + (long)b * M_ * D_ + (long)kc * 1024 * D_;   // [m][d]
  int t = threadIdx.x, l = t & 63, w = t >> 6;
  int l15 = l & 15, lg = l >> 4;
  int we = (w >> 2) * 64, wd = (w & 3) * 64;

  int am = (t >> 5) * 4;        // A m-rows am..am+3
  int ae = (t & 31) * 4;        // A e-cols ae..ae+3
  int bm = (t >> 6) * 8;        // B m-rows bm..bm+7
  int bd = (t & 63) * 4;        // B d-cols bd..bd+3

  fv4 acc[4][4] = {};
  fv4 pa[4], pb[8];

  auto LOAD = [&](int k0) {
#pragma unroll
    for (int r = 0; r < 4; ++r)
      pa[r] = *reinterpret_cast<const fv4*>(Ab + (long)(k0 + am + r) * E_ + r0 + ae);
#pragma unroll
    for (int r = 0; r < 8; ++r)
      pb[r] = *reinterpret_cast<const fv4*>(Bb + (long)(k0 + bm + r) * D_ + bd);
  };
  auto WRITE = [&](int buf) {
    int ga = am >> 3, offa = am & 7;
#pragma unroll
    for (int j = 0; j < 4; ++j) {
      int e = ae + j;
      int colw = ((ga ^ xf(e)) << 3) + offa;
      uint2 va;
      va.x = cvtpk(pa[0][j], pa[1][j]);
      va.y = cvtpk(pa[2][j], pa[3][j]);
      *reinterpret_cast<uint2*>(&As[buf][e][colw]) = va;
    }
    int gb = bm >> 3;
#pragma unroll
    for (int j = 0; j < 4; ++j) {
      int d = bd + j;
      int colw = (gb ^ xf(d)) << 3;
      uint4 vb;
      vb.x = cvtpk(pb[0][j], pb[1][j]);
      vb.y = cvtpk(pb[2][j], pb[3][j]);
      vb.z = cvtpk(pb[4][j], pb[5][j]);
      vb.w = cvtpk(pb[6][j], pb[7][j]);
      *reinterpret_cast<uint4*>(&Bs[buf][d][colw]) = vb;
    }
  };
  auto COMPUTE = [&](int buf) {
#pragma unroll
    for (int kk = 0; kk < 2; ++kk) {
      int gc = kk * 4 + lg;
      bh8 af[4], bf[4];
#pragma unroll
      for (int i = 0; i < 4; ++i) {
        int e = we + i * 16 + l15;
        af[i] = *reinterpret_cast<const bh8*>(&As[buf][e][(gc ^ xf(e)) << 3]);
      }
#pragma unroll
      for (int jj = 0; jj < 4; ++jj) {
        int d = wd + jj * 16 + l15;
        bf[jj] = *reinterpret_cast<const bh8*>(&Bs[buf][d][(gc ^ xf(d)) << 3]);
      }
#pragma unroll
      for (int i = 0; i < 4; ++i)
#pragma unroll
        for (int jj = 0; jj < 4; ++jj)
          acc[i][jj] = __builtin_amdgcn_mfma_f32_16x16x32_bf16(af[i], bf[jj], acc[i][jj], 0, 0, 0);
    }
  };

  LOAD(0);
  WRITE(0);
  __syncthreads();
  const int NIT = 16;  // 1024 / 64
  for (int kt = 0; kt < NIT; ++kt) {
    if (kt < NIT - 1) LOAD((kt + 1) * 64);
    COMPUTE(kt & 1);
    if (kt < NIT - 1) {
      WRITE((kt + 1) & 1);
      __syncthreads();
    }
  }

  float* Pp = P + ((long)(kc * B_ + b) * E_ + r0) * D_;
#pragma unroll
  for (int i = 0; i < 4; ++i)
#pragma unroll
    for (int jj = 0; jj < 4; ++jj)
#pragma unroll
      for (int q = 0; q < 4; ++q) {
        int row = we + i * 16 + lg * 4 + q;
        int col = wd + jj * 16 + l15;
        Pp[(long)row * D_ + col] = acc[i][jj][q];
      }
}

// ---------- reduce 4 split-K partials -> G bf16 ----------
__global__ __launch_bounds__(256) void k_red(const float* __restrict__ P, u16* __restrict__ G) {
  const long CS = (long)B_ * E_ * D_;
  long i = ((long)blockIdx.x * 256 + threadIdx.x) * 4;
  fv4 s0 = *reinterpret_cast<const fv4*>(P + i);
  fv4 s1 = *reinterpret_cast<const fv4*>(P + CS + i);
  fv4 s2 = *reinterpret_cast<const fv4*>(P + 2 * CS + i);
  fv4 s3 = *reinterpret_cast<const fv4*>(P + 3 * CS + i);
  fv4 sum = (s0 + s1) + (s2 + s3);
  uint2 o;
  o.x = cvtpk(sum[0], sum[1]);
  o.y = cvtpk(sum[2], sum[3]);
  *reinterpret_cast<uint2*>(G + i) = o;
}

// ---------- small-K GEMM: out = A' @ W^T (W read f32, converted on the fly) ----------
// MODE 2: A'=G bf16, write S f32 + per-block column softmax partial stats (seg y of 16).
// MODE 1: A'=H=G*exp(S-mx)*sv; mx/sv computed in prologue from mxp/smp (cstats fused);
//         ef = alpha*edge+(1-alpha)*C; fused z-partials -> zp.
template <int MODE>
__global__ __launch_bounds__(256, 2) void k_gemmS(
    const u16* __restrict__ A, const float* __restrict__ Wf,
    const float* __restrict__ Sin,
    float* __restrict__ Sout, float* __restrict__ mxp, float* __restrict__ smp,
    const float* __restrict__ edge, const float* __restrict__ alphap,
    float* __restrict__ outEF, const float* __restrict__ attw, float* __restrict__ zp) {
  __shared__ u16 As[2][64][72];
  __shared__ u16 Bs[2][64][72];
  __shared__ float sM[2][64], sS[2][64];
  __shared__ float sMx[D_], sSv[D_];
  int f = blockIdx.x;
  int b = f & 7, s = f >> 3;
  int x = s & 3, y = s >> 2;
  int r0 = y * 64, c0 = x * 64;
  const u16* Ab = A + (long)b * E_ * D_;
  int t = threadIdx.x, l = t & 63, w = t >> 6;
  int wr = w >> 1, wc = w & 1;
  int l15 = l & 15, lg = l >> 4;
  int rA = t >> 2, kA = (t & 3) * 16;

  if (MODE == 1) {
    float M = -3.0e38f;
#pragma unroll
    for (int s2 = 0; s2 < 16; ++s2) M = fmaxf(M, mxp[(b * 16 + s2) * D_ + t]);
    float Ssum = 0.f;
#pragma unroll
    for (int s2 = 0; s2 < 16; ++s2)
      Ssum += smp[(b * 16 + s2) * D_ + t] * __expf(mxp[(b * 16 + s2) * D_ + t] - M);
    sMx[t] = M;
    sSv[t] = 1.0f / Ssum;
  }
  __syncthreads();

  fv4 acc[2][2] = {};
  bh8 ga0[2], ga1[2];
  fv4 gb0[4], gb1[4];
  fv4 sa0[4], sa1[4];

  auto LOAD = [&](int k0, bh8 (&ga)[2], fv4 (&gb)[4], fv4 (&sa)[4]) {
    const u16* ap = Ab + (long)(r0 + rA) * D_ + k0 + kA;
    const float* bp = Wf + (long)(c0 + rA) * D_ + k0 + kA;
    ga[0] = *reinterpret_cast<const bh8*>(ap);
    ga[1] = *reinterpret_cast<const bh8*>(ap + 8);
#pragma unroll
    for (int i = 0; i < 4; ++i) gb[i] = *reinterpret_cast<const fv4*>(bp + i * 4);
    if (MODE == 1) {
      const float* sp2 = Sin + ((long)b * E_ + r0 + rA) * D_ + k0 + kA;
#pragma unroll
      for (int i = 0; i < 4; ++i) sa[i] = *reinterpret_cast<const fv4*>(sp2 + i * 4);
    }
  };
  auto WRITE = [&](const bh8 (&ga)[2], const fv4 (&gb)[4], const fv4 (&sa)[4], int buf, int k0) {
    if (MODE == 2) {
      *reinterpret_cast<bh8*>(&As[buf][rA][kA]) = ga[0];
      *reinterpret_cast<bh8*>(&As[buf][rA][kA + 8]) = ga[1];
    } else {
#pragma unroll
      for (int h = 0; h < 2; ++h) {
        fv4 mA = *reinterpret_cast<const fv4*>(&sMx[k0 + kA + h * 8]);
        fv4 mB = *reinterpret_cast<const fv4*>(&sMx[k0 + kA + h * 8 + 4]);
        fv4 vA = *reinterpret_cast<const fv4*>(&sSv[k0 + kA + h * 8]);
        fv4 vB = *reinterpret_cast<const fv4*>(&sSv[k0 + kA + h * 8 + 4]);
        float hf[8];
#pragma unroll
        for (int j = 0; j < 4; ++j) {
          hf[j]     = b2f((u16)ga[h][j])     * __expf(sa[h * 2][j]     - mA[j]) * vA[j];
          hf[4 + j] = b2f((u16)ga[h][j + 4]) * __expf(sa[h * 2 + 1][j] - mB[j]) * vB[j];
        }
        union { u32 w4[4]; bh8 v; } hp;
        hp.w4[0] = cvtpk(hf[0], hf[1]);
        hp.w4[1] = cvtpk(hf[2], hf[3]);
        hp.w4[2] = cvtpk(hf[4], hf[5]);
        hp.w4[3] = cvtpk(hf[6], hf[7]);
        *reinterpret_cast<bh8*>(&As[buf][rA][kA + h * 8]) = hp.v;
      }
    }
    union { u32 w4[4]; bh8 v; } wb0, wb1;
    wb0.w4[0] = cvtpk(gb[0][0], gb[0][1]);
    wb0.w4[1] = cvtpk(gb[0][2], gb[0][3]);
    wb0.w4[2] = cvtpk(gb[1][0], gb[1][1]);
    wb0.w4[3] = cvtpk(gb[1][2], gb[1][3]);
    wb1.w4[0] = cvtpk(gb[2][0], gb[2][1]);
    wb1.w4[1] = cvtpk(gb[2][2], gb[2][3]);
    wb1.w4[2] = cvtpk(gb[3][0], gb[3][1]);
    wb1.w4[3] = cvtpk(gb[3][2], gb[3][3]);
    *reinterpret_cast<bh8*>(&Bs[buf][rA][kA]) = wb0.v;
    *reinterpret_cast<bh8*>(&Bs[buf][rA][kA + 8]) = wb1.v;
  };
  auto COMPUTE = [&](int buf) {
#pragma unroll
    for (int kk = 0; kk < 2; ++kk) {
      bh8 af[2], bf[2];
#pragma unroll
      for (int i = 0; i < 2; ++i)
        af[i] = *reinterpret_cast<const bh8*>(&As[buf][wr * 32 + i * 16 + l15][kk * 32 + lg * 8]);
#pragma unroll
      for (int j = 0; j < 2; ++j)
        bf[j] = *reinterpret_cast<const bh8*>(&Bs[buf][wc * 32 + j * 16 + l15][kk * 32 + lg * 8]);
#pragma unroll
      for (int i = 0; i < 2; ++i)
#pragma unroll
        for (int j = 0; j < 2; ++j)
          acc[i][j] = __builtin_amdgcn_mfma_f32_16x16x32_bf16(af[i], bf[j], acc[i][j], 0, 0, 0);
    }
  };

  const int NT = D_ / 64;
  LOAD(0, ga0, gb0, sa0);
  LOAD(64, ga1, gb1, sa1);
  WRITE(ga0, gb0, sa0, 0, 0);
  __syncthreads();
  for (int kt = 0; kt < NT; kt += 2) {
    if (kt + 2 < NT) LOAD((kt + 2) * 64, ga0, gb0, sa0);
    COMPUTE(0);
    WRITE(ga1, gb1, sa1, 1, (kt + 1) * 64);
    __syncthreads();
    if (kt + 3 < NT) LOAD((kt + 3) * 64, ga1, gb1, sa1);
    COMPUTE(1);
    if (kt + 2 < NT) WRITE(ga0, gb0, sa0, 0, (kt + 2) * 64);
    __syncthreads();
  }

  if (MODE == 2) {
#pragma unroll
    for (int i = 0; i < 2; ++i)
#pragma unroll
      for (int j = 0; j < 2; ++j)
#pragma unroll
        for (int q = 0; q < 4; ++q) {
          int row = r0 + wr * 32 + i * 16 + lg * 4 + q;
          int col = c0 + wc * 32 + j * 16 + l15;
          Sout[((long)b * E_ + row) * D_ + col] = acc[i][j][q];
        }
#pragma unroll
    for (int j = 0; j < 2; ++j) {
      float m = -3.0e38f;
#pragma unroll
      for (int i = 0; i < 2; ++i)
#pragma unroll
        for (int q = 0; q < 4; ++q) m = fmaxf(m, acc[i][j][q]);
      m = fmaxf(m, __shfl_xor(m, 16));
      m = fmaxf(m, __shfl_xor(m, 32));
      float ssum = 0.f;
#pragma unroll
      for (int i = 0; i < 2; ++i)
#pragma unroll
        for (int q = 0; q < 4; ++q) ssum += __expf(acc[i][j][q] - m);
      ssum += __shfl_xor(ssum, 16);
      ssum += __shfl_xor(ssum, 32);
      if (lg == 0) {
        sM[wr][wc * 32 + j * 16 + l15] = m;
        sS[wr][wc * 32 + j * 16 + l15] = ssum;
      }
    }
    __syncthreads();
    if (t < 64) {
      float m0 = sM[0][t], m1 = sM[1][t];
      float M = fmaxf(m0, m1);
      float ss = sS[0][t] * __expf(m0 - M) + sS[1][t] * __expf(m1 - M);
      int idx = (b * 16 + y) * D_ + c0 + t;
      mxp[idx] = M;
      smp[idx] = ss;
    }
  } else {
    float al = *alphap, oneal = 1.0f - al;
    float aw0 = attw[c0 + wc * 32 + l15];
    float aw1 = attw[c0 + wc * 32 + 16 + l15];
#pragma unroll
    for (int i = 0; i < 2; ++i)
#pragma unroll
      for (int q = 0; q < 4; ++q) {
        int row = r0 + wr * 32 + i * 16 + lg * 4 + q;
        long idx0 = ((long)b * E_ + row) * D_ + c0 + wc * 32 + l15;
        long idx1 = idx0 + 16;
        float ef0 = al * edge[idx0] + oneal * acc[i][0][q];
        float ef1 = al * edge[idx1] + oneal * acc[i][1][q];
        outEF[idx0] = ef0;
        outEF[idx1] = ef1;
        float zv = ef0 * aw0 + ef1 * aw1;
        zv += __shfl_xor(zv, 1);
        zv += __shfl_xor(zv, 2);
        zv += __shfl_xor(zv, 4);
        zv += __shfl_xor(zv, 8);
        if (l15 == 0) zp[((long)(x * 2 + wc) * B_ + b) * E_ + row] = zv;
      }
  }
}

// ---------- tail A: redundant z-softmax + partial pooled over 128 e-rows ----------
__global__ __launch_bounds__(256) void k_tailA(const float* __restrict__ zp, const float* __restrict__ ef,
                                               float* __restrict__ pp) {
  int seg = blockIdx.x, b = blockIdx.y;
  int t = threadIdx.x;
  __shared__ float sZ[E_];
  __shared__ float wred[4];
  __shared__ float ps[4][D_];
  fv4 v = {};
#pragma unroll
  for (int s = 0; s < 8; ++s)
    v += *reinterpret_cast<const fv4*>(zp + ((long)s * B_ + b) * E_ + t * 4);
  *reinterpret_cast<fv4*>(&sZ[t * 4]) = v;
  float m = fmaxf(fmaxf(v[0], v[1]), fmaxf(v[2], v[3]));
#pragma unroll
  for (int off = 32; off; off >>= 1) m = fmaxf(m, __shfl_xor(m, off));
  if ((t & 63) == 0) wred[t >> 6] = m;
  __syncthreads();
  m = fmaxf(fmaxf(wred[0], wred[1]), fmaxf(wred[2], wred[3]));
  float e0 = __expf(v[0] - m), e1 = __expf(v[1] - m), e2 = __expf(v[2] - m), e3 = __expf(v[3] - m);
  float ssum = e0 + e1 + e2 + e3;
#pragma unroll
  for (int off = 32; off; off >>= 1) ssum += __shfl_xor(ssum, off);
  __syncthreads();
  if ((t & 63) == 0) wred[t >> 6] = ssum;
  __syncthreads();
  ssum = wred[0] + wred[1] + wred[2] + wred[3];
  float inv = 1.0f / ssum;
  fv4 az;
  az[0] = e0 * inv; az[1] = e1 * inv; az[2] = e2 * inv; az[3] = e3 * inv;
  __syncthreads();
  *reinterpret_cast<fv4*>(&sZ[t * 4]) = az;
  __syncthreads();
  int g = t >> 6, l = t & 63;
  fv4 a = {};
  const float* efb = ef + ((long)b * E_ + seg * 128 + g * 32) * D_ + l * 4;
  const float* azp = &sZ[seg * 128 + g * 32];
#pragma unroll 4
  for (int i = 0; i < 32; ++i)
    a += azp[i] * *reinterpret_cast<const fv4*>(efb + (long)i * D_);
  *reinterpret_cast<fv4*>(&ps[g][l * 4]) = a;
  __syncthreads();
  if (t < D_)
    pp[((long)b * 8 + seg) * D_ + t] = ps[0][t] + ps[1][t] + ps[2][t] + ps[3][t];
}

// ---------- tail B: pooled = sum segs; proj; fc -> logits ----------
__global__ __launch_bounds__(256) void k_tailB(const float* __restrict__ pp,
                                               const float* __restrict__ projw, const float* __restrict__ projb,
                                               const float* __restrict__ fcw, const float* __restrict__ fcb,
                                               float* __restrict__ outp) {
  int b = blockIdx.x, t = threadIdx.x;
  __shared__ float spl[D_], ov[D_];
  float a = 0.f;
#pragma unroll
  for (int s = 0; s < 8; ++s) a += pp[((long)b * 8 + s) * D_ + t];
  spl[t] = a;
  __syncthreads();
  float o = projb[t];
  const fv4* pw = reinterpret_cast<const fv4*>(projw + (long)t * D_);
#pragma unroll 8
  for (int dd = 0; dd < D_ / 4; ++dd) {
    fv4 wv = pw[dd];
    fv4 pv = *reinterpret_cast<const fv4*>(&spl[dd * 4]);
    o += wv[0] * pv[0] + wv[1] * pv[1] + wv[2] * pv[2] + wv[3] * pv[3];
  }
  ov[t] = o;
  __syncthreads();
  if (t < C_) {
    float lg = fcb[t];
    const fv4* fw = reinterpret_cast<const fv4*>(fcw + (long)t * D_);
#pragma unroll 8
    for (int dd = 0; dd < D_ / 4; ++dd) {
      fv4 wv = fw[dd];
      fv4 pv = *reinterpret_cast<const fv4*>(&ov[dd * 4]);
      lg += wv[0] * pv[0] + wv[1] * pv[1] + wv[2] * pv[2] + wv[3] * pv[3];
    }
    outp[b * C_ + t] = lg;
  }
}

extern "C" void kernel_launch(void* const* d_in, const int* in_sizes, int n_in,
                              void* d_out, int out_size, void* d_ws, size_t ws_size,
                              hipStream_t stream) {
  const float* node  = (const float*)d_in[0];
  const float* edge  = (const float*)d_in[1];
  const float* inc   = (const float*)d_in[2];
  const float* Wa    = (const float*)d_in[3];
  const float* Wp    = (const float*)d_in[4];
  const float* alpha = (const float*)d_in[5];
  const float* attw  = (const float*)d_in[6];
  const float* projw = (const float*)d_in[7];
  const float* projb = (const float*)d_in[8];
  const float* fcw   = (const float*)d_in[9];
  const float* fcb   = (const float*)d_in[10];
  float* outp = (float*)d_out;

  char* wsp = (char*)d_ws;
  size_t off = 0;
  auto alloc = [&](size_t bytes) {
    char* p = wsp + off;
    off += (bytes + 255) & ~(size_t)255;
    return (void*)p;
  };
  // P (4 x 8.4MB) dead after k_red; S and ef alias the region.
  float* P  = (float*)alloc((size_t)4 * B_ * E_ * D_ * 4);
  float* S  = P;                                  // written after k_red (P dead)
  float* ef = P + (size_t)2 * B_ * E_ * D_;       // written while S (lower half) is read
  u16* G    = (u16*)alloc((size_t)B_ * E_ * D_ * 2);
  float* mxp = (float*)alloc((size_t)B_ * 16 * D_ * 4);
  float* smp = (float*)alloc((size_t)B_ * 16 * D_ * 4);
  float* zp  = (float*)alloc((size_t)8 * B_ * E_ * 4);
  float* pp  = (float*)alloc((size_t)B_ * 8 * D_ * 4);

  // 1. split-K partials P[kc] = inc^T @ nf (r11 structure)
  k_gemm0<<<dim3(256), 512, 0, stream>>>(inc, node, P);
  // 2. reduce partials -> G bf16
  k_red<<<dim3((B_ * E_ * D_) / 1024), 256, 0, stream>>>(P, G);
  // 3. S = G @ Wa^T (f32, Wa converted on the fly) + partial column softmax stats
  k_gemmS<2><<<dim3(512), 256, 0, stream>>>(G, Wa, nullptr,
                                            S, mxp, smp, nullptr, nullptr, nullptr, nullptr, nullptr);
  // 4. ef = alpha*edge + (1-alpha)*((G*softmax) @ Wp^T); cstats + z-partials fused
  k_gemmS<1><<<dim3(512), 256, 0, stream>>>(G, Wp, S,
                                            nullptr, mxp, smp, edge, alpha, ef, attw, zp);
  // 5. tail A: redundant z-softmax + partial pooled (64 blocks)
  k_tailA<<<dim3(8, B_), 256, 0, stream>>>(zp, ef, pp);
  // 6. tail B: combine + proj + logits
  k_tailB<<<dim3(B_), 256, 0, stream>>>(pp, projw, projb, fcw, fcb, outp);
}